// Round 3
// baseline (3187.430 us; speedup 1.0000x reference)
//
#include <hip/hip_runtime.h>
#include <math.h>

#define PI_F 3.14159265358979323846f
#define EPSF 1e-6f

__device__ inline float2 cscale(float2 a, float s) { return make_float2(a.x * s, a.y * s); }

// ---------------- Stockham radix-2 FFT in LDS ----------------
// N points, T threads cooperate, SIGN=-1 forward / +1 inverse (unnormalized).
template <int N, int T, int SIGN>
__device__ inline float2* fft_lds(float2* bufA, float2* bufB, int tid) {
  const int NB = N / 2;
  const int BPT = NB / T;
  const int STAGES = (N == 1024) ? 10 : 8;
  float2* src = bufA;
  float2* dst = bufB;
  for (int s = 0; s < STAGES; ++s) {
    const int m = 1 << s;
    const int l = NB >> s;
    __syncthreads();
#pragma unroll
    for (int u = 0; u < BPT; ++u) {
      int bf = tid + u * T;
      int k = bf & (m - 1);
      int j = bf >> s;
      float2 a = src[bf];
      float2 c = src[bf + NB];
      float ang = (float)SIGN * PI_F * (float)j / (float)l;
      float wi, wr;
      sincosf(ang, &wi, &wr);
      float2 d0 = make_float2(a.x + c.x, a.y + c.y);
      float tx = a.x - c.x, ty = a.y - c.y;
      float2 d1 = make_float2(wr * tx - wi * ty, wr * ty + wi * tx);
      int o = 2 * bf - k;
      dst[o] = d0;
      dst[o + m] = d1;
    }
    float2* tmp = src; src = dst; dst = tmp;
  }
  __syncthreads();
  return src;
}

// ---------------- 1024-point passes (B=4 images) ----------------

__global__ __launch_bounds__(256) void k_fft_rows_big(
    const float* __restrict__ re, const float* __restrict__ im,
    float2* __restrict__ zf) {
  __shared__ float2 A[1024], Bb[1024];
  long base = (long)blockIdx.x * 1024;
  int tid = threadIdx.x;
#pragma unroll
  for (int k = 0; k < 4; ++k) {
    int q = tid + k * 256;
    A[q] = make_float2(re[base + q], im[base + q]);
  }
  float2* res = fft_lds<1024, 256, -1>(A, Bb, tid);
#pragma unroll
  for (int k = 0; k < 4; ++k) {
    int q = tid + k * 256;
    zf[base + ((q + 512) & 1023)] = res[q];
  }
}

__global__ __launch_bounds__(256) void k_fft_cols_big(float2* __restrict__ zf) {
  __shared__ float2 A[1024], Bb[1024];
  int b = blockIdx.x >> 10;
  int c = blockIdx.x & 1023;
  long base = (long)b * (1024 * 1024) + c;
  int tid = threadIdx.x;
#pragma unroll
  for (int k = 0; k < 4; ++k) {
    int i = tid + k * 256;
    A[i] = zf[base + (long)i * 1024];
  }
  float2* res = fft_lds<1024, 256, -1>(A, Bb, tid);
#pragma unroll
  for (int k = 0; k < 4; ++k) {
    int i = tid + k * 256;
    zf[base + (long)((i + 512) & 1023) * 1024] = res[i];
  }
}

__global__ __launch_bounds__(256) void k_ifft_rows_big(float2* __restrict__ U) {
  __shared__ float2 A[1024], Bb[1024];
  long base = (long)blockIdx.x * 1024;
  int tid = threadIdx.x;
#pragma unroll
  for (int k = 0; k < 4; ++k) {
    int q = tid + k * 256;
    A[q] = U[base + ((q + 512) & 1023)];
  }
  float2* res = fft_lds<1024, 256, 1>(A, Bb, tid);
  const float sc = 1.0f / 1024.0f;
#pragma unroll
  for (int k = 0; k < 4; ++k) {
    int q = tid + k * 256;
    U[base + q] = cscale(res[q], sc);
  }
}

__global__ __launch_bounds__(256) void k_ifft_cols_big(float2* __restrict__ U) {
  __shared__ float2 A[1024], Bb[1024];
  int b = blockIdx.x >> 10;
  int c = blockIdx.x & 1023;
  long base = (long)b * (1024 * 1024) + c;
  int tid = threadIdx.x;
#pragma unroll
  for (int k = 0; k < 4; ++k) {
    int i = tid + k * 256;
    A[i] = U[base + (long)((i + 512) & 1023) * 1024];
  }
  float2* res = fft_lds<1024, 256, 1>(A, Bb, tid);
  const float sc = 1.0f / 1024.0f;
#pragma unroll
  for (int k = 0; k < 4; ++k) {
    int i = tid + k * 256;
    U[base + (long)i * 1024] = cscale(res[i], sc);
  }
}

// ---------------- 256-point patch passes (per batch b, patch chunk l0..l0+nc) ----------------

__global__ __launch_bounds__(128) void k_patch_gather_irows(
    const float2* __restrict__ zf, const int* __restrict__ masks,
    const float* __restrict__ ctf, float2* __restrict__ P, int b, int l0) {
  __shared__ float2 A[256], Bb[256];
  int idx = blockIdx.x;  // li*256 + p
  int p = idx & 255;
  int li = idx >> 8;
  int l = l0 + li;
  int tid = threadIdx.x;
  int br = masks[2 * l] - 1, bc = masks[2 * l + 1] - 1;
  int sp = (p + 128) & 255;
  long zbase = (long)b * (1024 * 1024) + (long)(br + sp) * 1024 + bc;
  const float* crow = ctf + sp * 256;
#pragma unroll
  for (int k = 0; k < 2; ++k) {
    int q = tid + k * 128;
    int sq = (q + 128) & 255;
    float cv = crow[sq];
    float2 v = zf[zbase + sq];
    A[q] = make_float2(v.x * cv, v.y * cv);
  }
  float2* res = fft_lds<256, 128, 1>(A, Bb, tid);
  const float sc = 1.0f / 256.0f;
  long pbase = (long)idx * 256;
#pragma unroll
  for (int k = 0; k < 2; ++k) {
    int q = tid + k * 128;
    P[pbase + q] = cscale(res[q], sc);
  }
}

__global__ __launch_bounds__(128) void k_patch_icols_cz(
    float2* __restrict__ P, const float* __restrict__ Y, int b, int l0) {
  __shared__ float2 A[256], Bb[256];
  int idx = blockIdx.x;  // li*256 + q
  int q = idx & 255;
  int li = idx >> 8;
  int l = l0 + li;
  int tid = threadIdx.x;
  long pbase = (long)li * 65536 + q;
  const float* Yp = Y + ((long)b * 64 + l) * 65536 + q;
#pragma unroll
  for (int k = 0; k < 2; ++k) {
    int i = tid + k * 128;
    A[i] = P[pbase + (long)i * 256];
  }
  float2* res = fft_lds<256, 128, 1>(A, Bb, tid);
  const float sc = 1.0f / 256.0f;
#pragma unroll
  for (int k = 0; k < 2; ++k) {
    int i = tid + k * 128;
    float2 bz = cscale(res[i], sc);
    float mag = sqrtf(bz.x * bz.x + bz.y * bz.y);
    float s = sqrtf(Yp[(long)i * 256]);
    float2 ph = (mag > 0.0f) ? make_float2(bz.x / mag, bz.y / mag)
                             : make_float2(1.0f, 0.0f);
    P[pbase + (long)i * 256] = make_float2(bz.x - s * ph.x, bz.y - s * ph.y);
  }
}

__global__ __launch_bounds__(128) void k_patch_rows_f(float2* __restrict__ P) {
  __shared__ float2 A[256], Bb[256];
  long pbase = (long)blockIdx.x * 256;
  int tid = threadIdx.x;
#pragma unroll
  for (int k = 0; k < 2; ++k) {
    int q = tid + k * 128;
    A[q] = P[pbase + q];
  }
  float2* res = fft_lds<256, 128, -1>(A, Bb, tid);
#pragma unroll
  for (int k = 0; k < 2; ++k) {
    int q = tid + k * 128;
    P[pbase + ((q + 128) & 255)] = res[q];
  }
}

__global__ __launch_bounds__(128) void k_patch_cols_scatter(
    const float2* __restrict__ P, const int* __restrict__ masks,
    const float* __restrict__ ctf, float* __restrict__ U, int b, int l0) {
  __shared__ float2 A[256], Bb[256];
  int idx = blockIdx.x;  // li*256 + q
  int q = idx & 255;
  int li = idx >> 8;
  int l = l0 + li;
  int tid = threadIdx.x;
  int br = masks[2 * l] - 1, bc = masks[2 * l + 1] - 1;
  long pbase = (long)li * 65536 + q;
#pragma unroll
  for (int k = 0; k < 2; ++k) {
    int i = tid + k * 128;
    A[i] = P[pbase + (long)i * 256];
  }
  float2* res = fft_lds<256, 128, -1>(A, Bb, tid);
  const float sc = 1.0f / 64.0f;
#pragma unroll
  for (int k = 0; k < 2; ++k) {
    int i = tid + k * 128;       // pre-shift row index
    int p = (i + 128) & 255;     // shifted row index
    float cv = ctf[p * 256 + q] * sc;
    float2 v = res[i];
    long o = ((long)b * (1024 * 1024) + (long)(br + p) * 1024 + (bc + q)) * 2;
    atomicAdd(&U[o], v.x * cv);
    atomicAdd(&U[o + 1], v.y * cv);
  }
}

// ---------------- final combine ----------------
// Output layout: [im_ra : NTOT floats][Re(im_rc) : NTOT floats][Im(im_rc) : NTOT floats]
// (planar complex; imag-plane writes guarded so a real-only 2*NTOT layout also works)
__global__ __launch_bounds__(256) void k_combine(
    const float* __restrict__ Ia, const float* __restrict__ Icr,
    const float* __restrict__ Ici, const float2* __restrict__ W,
    const float* __restrict__ lamb, const float* __restrict__ eta1,
    float* __restrict__ out, long out_elems) {
  long i = (long)blockIdx.x * blockDim.x + threadIdx.x;
  const long NTOT = 4L * 1024 * 1024;
  float e1 = eta1[0], lm = lamb[0];
  float c1 = 100.0f * e1 * lm;
  float c2 = 10.0f * e1;
  float cr = Icr[i], ci = Ici[i], a = Ia[i];
  float mag = sqrtf(cr * cr + ci * ci);
  float t = a / (mag + EPSF);
  float2 w = W[i];
  float rx = cr * (1.0f - c1) + c1 * cr * t - c2 * w.x;
  float ry = ci * (1.0f - c1) + c1 * ci * t - c2 * w.y;
  if (i < out_elems) out[i] = sqrtf(rx * rx + ry * ry);
  if (NTOT + i < out_elems) out[NTOT + i] = rx;
  if (2 * NTOT + i < out_elems) out[2 * NTOT + i] = ry;
}

extern "C" void kernel_launch(void* const* d_in, const int* in_sizes, int n_in,
                              void* d_out, int out_size, void* d_ws, size_t ws_size,
                              hipStream_t stream) {
  (void)in_sizes; (void)n_in;
  const float* Ia   = (const float*)d_in[0];
  const float* Icr  = (const float*)d_in[1];
  const float* Ici  = (const float*)d_in[2];
  const float* Y    = (const float*)d_in[3];
  const int*   Masks = (const int*)d_in[4];
  const float* CTF  = (const float*)d_in[5];
  const float* lamb = (const float*)d_in[6];
  const float* eta1 = (const float*)d_in[7];
  float* out = (float*)d_out;

  const size_t MB32 = 32ull * 1024 * 1024;      // one [4,1024,1024] complex64 buffer
  const size_t PATCH_BYTES = 256 * 256 * sizeof(float2);  // 512 KiB per patch

  char* wsb = (char*)d_ws;
  // U accumulator: must live in ws (survives until combine writes d_out).
  float2* U = (float2*)wsb;
  size_t used = MB32;
  if (used > ws_size) used = ws_size;  // degenerate guard

  // zf: prefer ws; else alias d_out (consumed before combine writes out).
  float2* zf;
  bool zf_in_ws = (ws_size >= MB32 + MB32 + PATCH_BYTES);
  bool zf_in_out = (!zf_in_ws) && ((size_t)out_size * sizeof(float) >= MB32);
  if (zf_in_ws) { zf = (float2*)(wsb + used); used += MB32; }
  else if (zf_in_out) { zf = (float2*)d_out; }
  else { zf = U; }  // degenerate guard

  // P: patch chunk from remaining ws.
  size_t rem = (ws_size > used) ? (ws_size - used) : 0;
  long ncl = (long)(rem / PATCH_BYTES);
  int NC = (int)(ncl < 1 ? 1 : (ncl > 64 ? 64 : ncl));
  float2* P = (float2*)(wsb + ((rem >= PATCH_BYTES) ? used : 0));

  // zero the accumulator (clamped to the actual allocation)
  size_t zbytes = MB32 <= ws_size ? MB32 : ws_size;
  hipMemsetAsync(U, 0, zbytes, stream);

  k_fft_rows_big<<<4096, 256, 0, stream>>>(Icr, Ici, zf);
  k_fft_cols_big<<<4096, 256, 0, stream>>>(zf);

  for (int b = 0; b < 4; ++b) {
    for (int l0 = 0; l0 < 64; l0 += NC) {
      int nc = (64 - l0) < NC ? (64 - l0) : NC;
      k_patch_gather_irows<<<nc * 256, 128, 0, stream>>>(zf, Masks, CTF, P, b, l0);
      k_patch_icols_cz<<<nc * 256, 128, 0, stream>>>(P, Y, b, l0);
      k_patch_rows_f<<<nc * 256, 128, 0, stream>>>(P);
      k_patch_cols_scatter<<<nc * 256, 128, 0, stream>>>(P, Masks, CTF, (float*)U, b, l0);
    }
  }

  k_ifft_rows_big<<<4096, 256, 0, stream>>>(U);
  k_ifft_cols_big<<<4096, 256, 0, stream>>>(U);

  k_combine<<<16384, 256, 0, stream>>>(Ia, Icr, Ici, U, lamb, eta1, out, (long)out_size);
}

// Round 5
// 1880.194 us; speedup vs baseline: 1.6953x; 1.6953x over previous
//
#include <hip/hip_runtime.h>
#include <math.h>

#define PI_F 3.14159265358979323846f
#define EPSF 1e-6f

__device__ inline float2 cscale(float2 a, float s) { return make_float2(a.x * s, a.y * s); }

// ---------------- Stockham radix-2 FFT in LDS ----------------
// N points, T threads cooperate, SIGN=-1 forward / +1 inverse (unnormalized).
template <int N, int T, int SIGN>
__device__ inline float2* fft_lds(float2* bufA, float2* bufB, int tid) {
  const int NB = N / 2;
  const int BPT = NB / T;
  const int STAGES = (N == 1024) ? 10 : 8;
  float2* src = bufA;
  float2* dst = bufB;
  for (int s = 0; s < STAGES; ++s) {
    const int m = 1 << s;
    const int l = NB >> s;
    __syncthreads();
#pragma unroll
    for (int u = 0; u < BPT; ++u) {
      int bf = tid + u * T;
      int k = bf & (m - 1);
      int j = bf >> s;
      float2 a = src[bf];
      float2 c = src[bf + NB];
      float ang = (float)SIGN * PI_F * (float)j / (float)l;
      float wi, wr;
      sincosf(ang, &wi, &wr);
      float2 d0 = make_float2(a.x + c.x, a.y + c.y);
      float tx = a.x - c.x, ty = a.y - c.y;
      float2 d1 = make_float2(wr * tx - wi * ty, wr * ty + wi * tx);
      int o = 2 * bf - k;
      dst[o] = d0;
      dst[o + m] = d1;
    }
    float2* tmp = src; src = dst; dst = tmp;
  }
  __syncthreads();
  return src;
}

// ---------------- 1024-point passes (B=4 images) ----------------

__global__ __launch_bounds__(256) void k_fft_rows_big(
    const float* __restrict__ re, const float* __restrict__ im,
    float2* __restrict__ zf) {
  __shared__ float2 A[1024], Bb[1024];
  long base = (long)blockIdx.x * 1024;
  int tid = threadIdx.x;
#pragma unroll
  for (int k = 0; k < 4; ++k) {
    int q = tid + k * 256;
    A[q] = make_float2(re[base + q], im[base + q]);
  }
  float2* res = fft_lds<1024, 256, -1>(A, Bb, tid);
#pragma unroll
  for (int k = 0; k < 4; ++k) {
    int q = tid + k * 256;
    zf[base + ((q + 512) & 1023)] = res[q];
  }
}

__global__ __launch_bounds__(256) void k_fft_cols_big(float2* __restrict__ zf) {
  __shared__ float2 A[1024], Bb[1024];
  int b = blockIdx.x >> 10;
  int c = blockIdx.x & 1023;
  long base = (long)b * (1024 * 1024) + c;
  int tid = threadIdx.x;
#pragma unroll
  for (int k = 0; k < 4; ++k) {
    int i = tid + k * 256;
    A[i] = zf[base + (long)i * 1024];
  }
  float2* res = fft_lds<1024, 256, -1>(A, Bb, tid);
#pragma unroll
  for (int k = 0; k < 4; ++k) {
    int i = tid + k * 256;
    zf[base + (long)((i + 512) & 1023) * 1024] = res[i];
  }
}

__global__ __launch_bounds__(256) void k_ifft_rows_big(float2* __restrict__ U) {
  __shared__ float2 A[1024], Bb[1024];
  long base = (long)blockIdx.x * 1024;
  int tid = threadIdx.x;
#pragma unroll
  for (int k = 0; k < 4; ++k) {
    int q = tid + k * 256;
    A[q] = U[base + ((q + 512) & 1023)];
  }
  float2* res = fft_lds<1024, 256, 1>(A, Bb, tid);
  const float sc = 1.0f / 1024.0f;
#pragma unroll
  for (int k = 0; k < 4; ++k) {
    int q = tid + k * 256;
    U[base + q] = cscale(res[q], sc);
  }
}

__global__ __launch_bounds__(256) void k_ifft_cols_big(float2* __restrict__ U) {
  __shared__ float2 A[1024], Bb[1024];
  int b = blockIdx.x >> 10;
  int c = blockIdx.x & 1023;
  long base = (long)b * (1024 * 1024) + c;
  int tid = threadIdx.x;
#pragma unroll
  for (int k = 0; k < 4; ++k) {
    int i = tid + k * 256;
    A[i] = U[base + (long)((i + 512) & 1023) * 1024];
  }
  float2* res = fft_lds<1024, 256, 1>(A, Bb, tid);
  const float sc = 1.0f / 1024.0f;
#pragma unroll
  for (int k = 0; k < 4; ++k) {
    int i = tid + k * 256;
    U[base + (long)i * 1024] = cscale(res[i], sc);
  }
}

// ---------------- 256-point patch passes (per batch b, chunk l0..l0+nc) ----------------

// pass 1: gather (ifftshift fold) * CTF, inverse ROW FFT, scale 1/256 -> P rows
__global__ __launch_bounds__(128) void k_patch_gather_irows(
    const float2* __restrict__ zf, const int* __restrict__ masks,
    const float* __restrict__ ctf, float2* __restrict__ P, int b, int l0) {
  __shared__ float2 A[256], Bb[256];
  int idx = blockIdx.x;  // li*256 + p
  int p = idx & 255;
  int li = idx >> 8;
  int l = l0 + li;
  int tid = threadIdx.x;
  int br = masks[2 * l] - 1, bc = masks[2 * l + 1] - 1;
  int sp = (p + 128) & 255;
  long zbase = (long)b * (1024 * 1024) + (long)(br + sp) * 1024 + bc;
  const float* crow = ctf + sp * 256;
#pragma unroll
  for (int k = 0; k < 2; ++k) {
    int q = tid + k * 128;
    int sq = (q + 128) & 255;
    float cv = crow[sq];
    float2 v = zf[zbase + sq];
    A[q] = make_float2(v.x * cv, v.y * cv);
  }
  float2* res = fft_lds<256, 128, 1>(A, Bb, tid);
  const float sc = 1.0f / 256.0f;
  long pbase = (long)idx * 256;
#pragma unroll
  for (int k = 0; k < 2; ++k) {
    int q = tid + k * 128;
    P[pbase + q] = cscale(res[q], sc);
  }
}

// pass 2: inverse COL FFT (1/256) -> Bz; Cz = Bz - sqrt(Y)*Bz/|Bz| (in place, row-major P)
__global__ __launch_bounds__(128) void k_patch_icols_cz(
    float2* __restrict__ P, const float* __restrict__ Y, int b, int l0) {
  __shared__ float2 A[256], Bb[256];
  int idx = blockIdx.x;  // li*256 + q
  int q = idx & 255;
  int li = idx >> 8;
  int l = l0 + li;
  int tid = threadIdx.x;
  long pbase = (long)li * 65536 + q;
  const float* Yp = Y + ((long)b * 64 + l) * 65536 + q;
#pragma unroll
  for (int k = 0; k < 2; ++k) {
    int i = tid + k * 128;
    A[i] = P[pbase + (long)i * 256];
  }
  float2* res = fft_lds<256, 128, 1>(A, Bb, tid);
  const float sc = 1.0f / 256.0f;
#pragma unroll
  for (int k = 0; k < 2; ++k) {
    int i = tid + k * 128;
    float2 bz = cscale(res[i], sc);
    float mag = sqrtf(bz.x * bz.x + bz.y * bz.y);
    float s = sqrtf(Yp[(long)i * 256]);
    float2 ph = (mag > 0.0f) ? make_float2(bz.x / mag, bz.y / mag)
                             : make_float2(1.0f, 0.0f);
    P[pbase + (long)i * 256] = make_float2(bz.x - s * ph.x, bz.y - s * ph.y);
  }
}

// pass 3: forward COL FFT of Cz; write back column with ROW fftshift fold
__global__ __launch_bounds__(128) void k_patch_cols_f(
    float2* __restrict__ P) {
  __shared__ float2 A[256], Bb[256];
  int idx = blockIdx.x;  // li*256 + q
  int q = idx & 255;
  int li = idx >> 8;
  int tid = threadIdx.x;
  long pbase = (long)li * 65536 + q;
#pragma unroll
  for (int k = 0; k < 2; ++k) {
    int i = tid + k * 128;
    A[i] = P[pbase + (long)i * 256];
  }
  float2* res = fft_lds<256, 128, -1>(A, Bb, tid);
#pragma unroll
  for (int k = 0; k < 2; ++k) {
    int i = tid + k * 128;
    P[pbase + (long)((i + 128) & 255) * 256] = res[i];  // row-shift fold
  }
}

// pass 4: forward ROW FFT; col fftshift fold; * ctf * (1/L); COALESCED row scatter
__global__ __launch_bounds__(128) void k_patch_rows_scatter(
    const float2* __restrict__ P, const int* __restrict__ masks,
    const float* __restrict__ ctf, float* __restrict__ U, int b, int l0) {
  __shared__ float2 A[256], Bb[256];
  int idx = blockIdx.x;  // li*256 + p   (p = shifted freq row)
  int p = idx & 255;
  int li = idx >> 8;
  int l = l0 + li;
  int tid = threadIdx.x;
  int br = masks[2 * l] - 1, bc = masks[2 * l + 1] - 1;
  long pbase = (long)idx * 256;
#pragma unroll
  for (int k = 0; k < 2; ++k) {
    int q = tid + k * 128;
    A[q] = P[pbase + q];
  }
  float2* res = fft_lds<256, 128, -1>(A, Bb, tid);
  const float sc = 1.0f / 64.0f;
  long rowbase = ((long)b * (1024 * 1024) + (long)(br + p) * 1024 + bc) * 2;
  const float* crow = ctf + p * 256;
#pragma unroll
  for (int k = 0; k < 2; ++k) {
    int q = tid + k * 128;
    int qp = (q + 128) & 255;  // shifted col index -> lanes write consecutive addrs
    float cv = crow[qp] * sc;
    float2 v = res[q];
    atomicAdd(&U[rowbase + 2 * qp], v.x * cv);
    atomicAdd(&U[rowbase + 2 * qp + 1], v.y * cv);
  }
}

// ---------------- final combine ----------------
// Output layout: [im_ra : NTOT][Re(im_rc) : NTOT][Im(im_rc) : NTOT] (planar, guarded)
__global__ __launch_bounds__(256) void k_combine(
    const float* __restrict__ Ia, const float* __restrict__ Icr,
    const float* __restrict__ Ici, const float2* __restrict__ W,
    const float* __restrict__ lamb, const float* __restrict__ eta1,
    float* __restrict__ out, long out_elems) {
  long i = (long)blockIdx.x * blockDim.x + threadIdx.x;
  const long NTOT = 4L * 1024 * 1024;
  float e1 = eta1[0], lm = lamb[0];
  float c1 = 100.0f * e1 * lm;
  float c2 = 10.0f * e1;
  float cr = Icr[i], ci = Ici[i], a = Ia[i];
  float mag = sqrtf(cr * cr + ci * ci);
  float t = a / (mag + EPSF);
  float2 w = W[i];
  float rx = cr * (1.0f - c1) + c1 * cr * t - c2 * w.x;
  float ry = ci * (1.0f - c1) + c1 * ci * t - c2 * w.y;
  if (i < out_elems) out[i] = sqrtf(rx * rx + ry * ry);
  if (NTOT + i < out_elems) out[NTOT + i] = rx;
  if (2 * NTOT + i < out_elems) out[2 * NTOT + i] = ry;
}

extern "C" void kernel_launch(void* const* d_in, const int* in_sizes, int n_in,
                              void* d_out, int out_size, void* d_ws, size_t ws_size,
                              hipStream_t stream) {
  (void)in_sizes; (void)n_in;
  const float* Ia   = (const float*)d_in[0];
  const float* Icr  = (const float*)d_in[1];
  const float* Ici  = (const float*)d_in[2];
  const float* Y    = (const float*)d_in[3];
  const int*   Masks = (const int*)d_in[4];
  const float* CTF  = (const float*)d_in[5];
  const float* lamb = (const float*)d_in[6];
  const float* eta1 = (const float*)d_in[7];
  float* out = (float*)d_out;

  const size_t MB32 = 32ull * 1024 * 1024;      // one [4,1024,1024] complex64 buffer
  const size_t PATCH_BYTES = 256 * 256 * sizeof(float2);  // 512 KiB per patch

  char* wsb = (char*)d_ws;
  // U accumulator: must live in ws (survives until combine writes d_out).
  float2* U = (float2*)wsb;
  size_t used = MB32;
  if (used > ws_size) used = ws_size;  // degenerate guard

  // zf: prefer ws; else alias d_out (consumed before combine writes out).
  float2* zf;
  bool zf_in_ws = (ws_size >= MB32 + MB32 + PATCH_BYTES);
  bool zf_in_out = (!zf_in_ws) && ((size_t)out_size * sizeof(float) >= MB32);
  if (zf_in_ws) { zf = (float2*)(wsb + used); used += MB32; }
  else if (zf_in_out) { zf = (float2*)d_out; }
  else { zf = U; }  // degenerate guard

  // P: patch chunk from remaining ws.
  size_t rem = (ws_size > used) ? (ws_size - used) : 0;
  long ncl = (long)(rem / PATCH_BYTES);
  int NC = (int)(ncl < 1 ? 1 : (ncl > 64 ? 64 : ncl));
  float2* P = (float2*)(wsb + ((rem >= PATCH_BYTES) ? used : 0));

  // zero the accumulator (clamped to the actual allocation)
  size_t zbytes = MB32 <= ws_size ? MB32 : ws_size;
  hipMemsetAsync(U, 0, zbytes, stream);

  k_fft_rows_big<<<4096, 256, 0, stream>>>(Icr, Ici, zf);
  k_fft_cols_big<<<4096, 256, 0, stream>>>(zf);

  for (int b = 0; b < 4; ++b) {
    for (int l0 = 0; l0 < 64; l0 += NC) {
      int nc = (64 - l0) < NC ? (64 - l0) : NC;
      k_patch_gather_irows<<<nc * 256, 128, 0, stream>>>(zf, Masks, CTF, P, b, l0);
      k_patch_icols_cz<<<nc * 256, 128, 0, stream>>>(P, Y, b, l0);
      k_patch_cols_f<<<nc * 256, 128, 0, stream>>>(P);
      k_patch_rows_scatter<<<nc * 256, 128, 0, stream>>>(P, Masks, CTF, (float*)U, b, l0);
    }
  }

  k_ifft_rows_big<<<4096, 256, 0, stream>>>(U);
  k_ifft_cols_big<<<4096, 256, 0, stream>>>(U);

  k_combine<<<16384, 256, 0, stream>>>(Ia, Icr, Ici, U, lamb, eta1, out, (long)out_size);
}

// Round 6
// 1777.702 us; speedup vs baseline: 1.7930x; 1.0577x over previous
//
#include <hip/hip_runtime.h>
#include <math.h>

#define PI_F 3.14159265358979323846f
#define EPSF 1e-6f

__device__ inline float2 cscale(float2 a, float s) { return make_float2(a.x * s, a.y * s); }

// ---------------- Stockham radix-2 FFT in LDS ----------------
template <int N, int T, int SIGN>
__device__ inline float2* fft_lds(float2* bufA, float2* bufB, int tid) {
  const int NB = N / 2;
  const int BPT = NB / T;
  const int STAGES = (N == 1024) ? 10 : 8;
  float2* src = bufA;
  float2* dst = bufB;
  for (int s = 0; s < STAGES; ++s) {
    const int m = 1 << s;
    const int l = NB >> s;
    __syncthreads();
#pragma unroll
    for (int u = 0; u < BPT; ++u) {
      int bf = tid + u * T;
      int k = bf & (m - 1);
      int j = bf >> s;
      float2 a = src[bf];
      float2 c = src[bf + NB];
      float ang = (float)SIGN * PI_F * (float)j / (float)l;
      float wi, wr;
      sincosf(ang, &wi, &wr);
      float2 d0 = make_float2(a.x + c.x, a.y + c.y);
      float tx = a.x - c.x, ty = a.y - c.y;
      float2 d1 = make_float2(wr * tx - wi * ty, wr * ty + wi * tx);
      int o = 2 * bf - k;
      dst[o] = d0;
      dst[o + m] = d1;
    }
    float2* tmp = src; src = dst; dst = tmp;
  }
  __syncthreads();
  return src;
}

// ---------------- per-batch: YT[l,q,p] = sqrt(Y[b,l,p,q]) as fp16 ----------------
__global__ __launch_bounds__(256) void k_sqrty_bt(
    const float* __restrict__ Y, _Float16* __restrict__ YT, int b) {
  __shared__ float T[32][33];
  int blk = blockIdx.x;          // l*64 + tp*8 + tq
  int tq = blk & 7;
  int tp = (blk >> 3) & 7;
  int l = blk >> 6;              // 0..63
  int tx = threadIdx.x & 31;
  int ty = threadIdx.x >> 5;     // 0..7
  const float* Yb = Y + ((long)b * 64 + l) * 65536;
  _Float16* Tb = YT + (long)l * 65536;
#pragma unroll
  for (int k = 0; k < 4; ++k) {
    int p = tp * 32 + ty + k * 8;
    T[ty + k * 8][tx] = Yb[p * 256 + tq * 32 + tx];
  }
  __syncthreads();
#pragma unroll
  for (int k = 0; k < 4; ++k) {
    int q = tq * 32 + ty + k * 8;
    Tb[(long)q * 256 + tp * 32 + tx] = (_Float16)sqrtf(T[tx][ty + k * 8]);
  }
}

// ---------------- 1024-point passes (B=4 images) ----------------

__global__ __launch_bounds__(256) void k_fft_rows_big(
    const float* __restrict__ re, const float* __restrict__ im,
    float2* __restrict__ zf) {
  __shared__ float2 A[1024], Bb[1024];
  long base = (long)blockIdx.x * 1024;
  int tid = threadIdx.x;
#pragma unroll
  for (int k = 0; k < 4; ++k) {
    int q = tid + k * 256;
    A[q] = make_float2(re[base + q], im[base + q]);
  }
  float2* res = fft_lds<1024, 256, -1>(A, Bb, tid);
#pragma unroll
  for (int k = 0; k < 4; ++k) {
    int q = tid + k * 256;
    zf[base + ((q + 512) & 1023)] = res[q];
  }
}

__global__ __launch_bounds__(256) void k_fft_cols_big(float2* __restrict__ zf) {
  __shared__ float2 A[1024], Bb[1024];
  int b = blockIdx.x >> 10;
  int c = blockIdx.x & 1023;
  long base = (long)b * (1024 * 1024) + c;
  int tid = threadIdx.x;
#pragma unroll
  for (int k = 0; k < 4; ++k) {
    int i = tid + k * 256;
    A[i] = zf[base + (long)i * 1024];
  }
  float2* res = fft_lds<1024, 256, -1>(A, Bb, tid);
#pragma unroll
  for (int k = 0; k < 4; ++k) {
    int i = tid + k * 256;
    zf[base + (long)((i + 512) & 1023) * 1024] = res[i];
  }
}

__global__ __launch_bounds__(256) void k_ifft_rows_big(float2* __restrict__ U) {
  __shared__ float2 A[1024], Bb[1024];
  long base = (long)blockIdx.x * 1024;
  int tid = threadIdx.x;
#pragma unroll
  for (int k = 0; k < 4; ++k) {
    int q = tid + k * 256;
    A[q] = U[base + ((q + 512) & 1023)];
  }
  float2* res = fft_lds<1024, 256, 1>(A, Bb, tid);
  const float sc = 1.0f / 1024.0f;
#pragma unroll
  for (int k = 0; k < 4; ++k) {
    int q = tid + k * 256;
    U[base + q] = cscale(res[q], sc);
  }
}

__global__ __launch_bounds__(256) void k_ifft_cols_big(float2* __restrict__ U) {
  __shared__ float2 A[1024], Bb[1024];
  int b = blockIdx.x >> 10;
  int c = blockIdx.x & 1023;
  long base = (long)b * (1024 * 1024) + c;
  int tid = threadIdx.x;
#pragma unroll
  for (int k = 0; k < 4; ++k) {
    int i = tid + k * 256;
    A[i] = U[base + (long)((i + 512) & 1023) * 1024];
  }
  float2* res = fft_lds<1024, 256, 1>(A, Bb, tid);
  const float sc = 1.0f / 1024.0f;
#pragma unroll
  for (int k = 0; k < 4; ++k) {
    int i = tid + k * 256;
    U[base + (long)i * 1024] = cscale(res[i], sc);
  }
}

// ---------------- 256-point patch passes (per batch b, chunk l0..l0+nc) ----------------

// pass 1: gather (ifftshift fold) * CTF, inverse ROW FFT, scale 1/256 -> P rows
__global__ __launch_bounds__(128) void k_patch_gather_irows(
    const float2* __restrict__ zf, const int* __restrict__ masks,
    const float* __restrict__ ctf, float2* __restrict__ P, int b, int l0) {
  __shared__ float2 A[256], Bb[256];
  int idx = blockIdx.x;  // li*256 + p
  int p = idx & 255;
  int li = idx >> 8;
  int l = l0 + li;
  int tid = threadIdx.x;
  int br = masks[2 * l] - 1, bc = masks[2 * l + 1] - 1;
  int sp = (p + 128) & 255;
  long zbase = (long)b * (1024 * 1024) + (long)(br + sp) * 1024 + bc;
  const float* crow = ctf + sp * 256;
#pragma unroll
  for (int k = 0; k < 2; ++k) {
    int q = tid + k * 128;
    int sq = (q + 128) & 255;
    float cv = crow[sq];
    float2 v = zf[zbase + sq];
    A[q] = make_float2(v.x * cv, v.y * cv);
  }
  float2* res = fft_lds<256, 128, 1>(A, Bb, tid);
  const float sc = 1.0f / 256.0f;
  long pbase = (long)idx * 256;
#pragma unroll
  for (int k = 0; k < 2; ++k) {
    int q = tid + k * 128;
    P[pbase + q] = cscale(res[q], sc);
  }
}

// pass 2: inverse COL FFT (1/256) -> Bz; Cz = Bz - sqrt(Y)*Bz/|Bz| (in place)
__global__ __launch_bounds__(128) void k_patch_icols_cz(
    float2* __restrict__ P, const float* __restrict__ Y,
    const _Float16* __restrict__ YT, int use_yt, int b, int l0) {
  __shared__ float2 A[256], Bb[256];
  int idx = blockIdx.x;  // li*256 + q
  int q = idx & 255;
  int li = idx >> 8;
  int l = l0 + li;
  int tid = threadIdx.x;
  long pbase = (long)li * 65536 + q;
#pragma unroll
  for (int k = 0; k < 2; ++k) {
    int i = tid + k * 128;
    A[i] = P[pbase + (long)i * 256];
  }
  float2* res = fft_lds<256, 128, 1>(A, Bb, tid);
  const float sc = 1.0f / 256.0f;
  const float* Yp = Y + ((long)b * 64 + l) * 65536 + q;
  const _Float16* Yt = YT + ((long)l * 256 + q) * 256;  // coalesced in i
#pragma unroll
  for (int k = 0; k < 2; ++k) {
    int i = tid + k * 128;
    float2 bz = cscale(res[i], sc);
    float mag = sqrtf(bz.x * bz.x + bz.y * bz.y);
    float s = use_yt ? (float)Yt[i] : sqrtf(Yp[(long)i * 256]);
    float2 ph = (mag > 0.0f) ? make_float2(bz.x / mag, bz.y / mag)
                             : make_float2(1.0f, 0.0f);
    P[pbase + (long)i * 256] = make_float2(bz.x - s * ph.x, bz.y - s * ph.y);
  }
}

// pass 3: forward COL FFT of Cz; write back column with ROW fftshift fold
__global__ __launch_bounds__(128) void k_patch_cols_f(
    float2* __restrict__ P) {
  __shared__ float2 A[256], Bb[256];
  int idx = blockIdx.x;  // li*256 + q
  int q = idx & 255;
  int li = idx >> 8;
  int tid = threadIdx.x;
  long pbase = (long)li * 65536 + q;
#pragma unroll
  for (int k = 0; k < 2; ++k) {
    int i = tid + k * 128;
    A[i] = P[pbase + (long)i * 256];
  }
  float2* res = fft_lds<256, 128, -1>(A, Bb, tid);
#pragma unroll
  for (int k = 0; k < 2; ++k) {
    int i = tid + k * 128;
    P[pbase + (long)((i + 128) & 255) * 256] = res[i];  // row-shift fold
  }
}

// pass 4: forward ROW FFT; col fftshift fold; * ctf * (1/L); coalesced row scatter
__global__ __launch_bounds__(128) void k_patch_rows_scatter(
    const float2* __restrict__ P, const int* __restrict__ masks,
    const float* __restrict__ ctf, float* __restrict__ U, int b, int l0) {
  __shared__ float2 A[256], Bb[256];
  int idx = blockIdx.x;  // li*256 + p   (p = shifted freq row)
  int p = idx & 255;
  int li = idx >> 8;
  int l = l0 + li;
  int tid = threadIdx.x;
  int br = masks[2 * l] - 1, bc = masks[2 * l + 1] - 1;
  long pbase = (long)idx * 256;
#pragma unroll
  for (int k = 0; k < 2; ++k) {
    int q = tid + k * 128;
    A[q] = P[pbase + q];
  }
  float2* res = fft_lds<256, 128, -1>(A, Bb, tid);
  const float sc = 1.0f / 64.0f;
  long rowbase = ((long)b * (1024 * 1024) + (long)(br + p) * 1024 + bc) * 2;
  const float* crow = ctf + p * 256;
#pragma unroll
  for (int k = 0; k < 2; ++k) {
    int q = tid + k * 128;
    int qp = (q + 128) & 255;  // shifted col index -> lanes write consecutive addrs
    float cv = crow[qp] * sc;
    float2 v = res[q];
    atomicAdd(&U[rowbase + 2 * qp], v.x * cv);
    atomicAdd(&U[rowbase + 2 * qp + 1], v.y * cv);
  }
}

// ---------------- final combine ----------------
__global__ __launch_bounds__(256) void k_combine(
    const float* __restrict__ Ia, const float* __restrict__ Icr,
    const float* __restrict__ Ici, const float2* __restrict__ W,
    const float* __restrict__ lamb, const float* __restrict__ eta1,
    float* __restrict__ out, long out_elems) {
  long i = (long)blockIdx.x * blockDim.x + threadIdx.x;
  const long NTOT = 4L * 1024 * 1024;
  float e1 = eta1[0], lm = lamb[0];
  float c1 = 100.0f * e1 * lm;
  float c2 = 10.0f * e1;
  float cr = Icr[i], ci = Ici[i], a = Ia[i];
  float mag = sqrtf(cr * cr + ci * ci);
  float t = a / (mag + EPSF);
  float2 w = W[i];
  float rx = cr * (1.0f - c1) + c1 * cr * t - c2 * w.x;
  float ry = ci * (1.0f - c1) + c1 * ci * t - c2 * w.y;
  if (i < out_elems) out[i] = sqrtf(rx * rx + ry * ry);
  if (NTOT + i < out_elems) out[NTOT + i] = rx;
  if (2 * NTOT + i < out_elems) out[2 * NTOT + i] = ry;
}

extern "C" void kernel_launch(void* const* d_in, const int* in_sizes, int n_in,
                              void* d_out, int out_size, void* d_ws, size_t ws_size,
                              hipStream_t stream) {
  (void)in_sizes; (void)n_in;
  const float* Ia   = (const float*)d_in[0];
  const float* Icr  = (const float*)d_in[1];
  const float* Ici  = (const float*)d_in[2];
  const float* Y    = (const float*)d_in[3];
  const int*   Masks = (const int*)d_in[4];
  const float* CTF  = (const float*)d_in[5];
  const float* lamb = (const float*)d_in[6];
  const float* eta1 = (const float*)d_in[7];
  float* out = (float*)d_out;

  const size_t MB32 = 32ull * 1024 * 1024;
  const size_t YTB  = 8ull * 1024 * 1024;               // per-batch fp16 sqrt(Y)^T
  const size_t PATCH_BYTES = 256 * 256 * sizeof(float2);  // 512 KiB

  char* wsb = (char*)d_ws;
  float2* U = (float2*)wsb;        // accumulator, survives to the end
  size_t used = MB32;
  if (used > ws_size) used = ws_size;

  // zf placement: identical policy to the passing round-5 kernel.
  float2* zf;
  bool zf_in_ws = (ws_size >= MB32 + MB32 + PATCH_BYTES);
  bool zf_in_out = (!zf_in_ws) && ((size_t)out_size * sizeof(float) >= MB32);
  if (zf_in_ws) { zf = (float2*)(wsb + used); used += MB32; }
  else if (zf_in_out) { zf = (float2*)d_out; }
  else { zf = U; }

  // YT: only if it fits after U/zf with >=1 patch left.
  _Float16* YT = nullptr;
  int use_yt = 0;
  if (ws_size >= used + YTB + PATCH_BYTES) {
    YT = (_Float16*)(wsb + used);
    used += YTB;
    use_yt = 1;
  }

  size_t rem = (ws_size > used) ? (ws_size - used) : 0;
  long ncl = (long)(rem / PATCH_BYTES);
  int NC = (int)(ncl < 1 ? 1 : (ncl > 64 ? 64 : ncl));
  float2* P = (float2*)(wsb + ((rem >= PATCH_BYTES) ? used : 0));

  size_t zbytes = MB32 <= ws_size ? MB32 : ws_size;
  hipMemsetAsync(U, 0, zbytes, stream);

  k_fft_rows_big<<<4096, 256, 0, stream>>>(Icr, Ici, zf);
  k_fft_cols_big<<<4096, 256, 0, stream>>>(zf);

  for (int b = 0; b < 4; ++b) {
    if (use_yt) k_sqrty_bt<<<4096, 256, 0, stream>>>(Y, YT, b);
    for (int l0 = 0; l0 < 64; l0 += NC) {
      int nc = (64 - l0) < NC ? (64 - l0) : NC;
      k_patch_gather_irows<<<nc * 256, 128, 0, stream>>>(zf, Masks, CTF, P, b, l0);
      k_patch_icols_cz<<<nc * 256, 128, 0, stream>>>(P, Y, YT, use_yt, b, l0);
      k_patch_cols_f<<<nc * 256, 128, 0, stream>>>(P);
      k_patch_rows_scatter<<<nc * 256, 128, 0, stream>>>(P, Masks, CTF, (float*)U, b, l0);
    }
  }

  k_ifft_rows_big<<<4096, 256, 0, stream>>>(U);
  k_ifft_cols_big<<<4096, 256, 0, stream>>>(U);

  k_combine<<<16384, 256, 0, stream>>>(Ia, Icr, Ici, U, lamb, eta1, out, (long)out_size);
}

// Round 7
// 1031.050 us; speedup vs baseline: 3.0914x; 1.7242x over previous
//
#include <hip/hip_runtime.h>
#include <math.h>

#define PI_F 3.14159265358979323846f
#define EPSF 1e-6f

__device__ inline float2 cscale(float2 a, float s) { return make_float2(a.x * s, a.y * s); }

// ---------------- Stockham radix-2 FFT in LDS (single column; used by row passes) ----------------
template <int N, int T, int SIGN>
__device__ inline float2* fft_lds(float2* bufA, float2* bufB, int tid) {
  const int NB = N / 2;
  const int BPT = NB / T;
  const int STAGES = (N == 1024) ? 10 : 8;
  float2* src = bufA;
  float2* dst = bufB;
  for (int s = 0; s < STAGES; ++s) {
    const int m = 1 << s;
    const int l = NB >> s;
    __syncthreads();
#pragma unroll
    for (int u = 0; u < BPT; ++u) {
      int bf = tid + u * T;
      int k = bf & (m - 1);
      int j = bf >> s;
      float2 a = src[bf];
      float2 c = src[bf + NB];
      float ang = (float)SIGN * PI_F * (float)j / (float)l;
      float wi, wr;
      sincosf(ang, &wi, &wr);
      float2 d0 = make_float2(a.x + c.x, a.y + c.y);
      float tx = a.x - c.x, ty = a.y - c.y;
      float2 d1 = make_float2(wr * tx - wi * ty, wr * ty + wi * tx);
      int o = 2 * bf - k;
      dst[o] = d0;
      dst[o + m] = d1;
    }
    float2* tmp = src; src = dst; dst = tmp;
  }
  __syncthreads();
  return src;
}

// ---------------- in-place multi-column FFTs (column passes) ----------------
// Layout: A[i*CW + c], i = transform index, c = column within group.
// DIF: natural input -> bit-reversed output.  DIT: bit-reversed input -> natural output.
template <int N, int CW, int T, int SIGN>
__device__ inline void dif_mc(float2* A, int tid) {
  const int NB = N / 2;
  const int LOG = (N == 1024) ? 10 : 8;
  const int ITER = (NB * CW) / T;
  const int BSTR = T / CW;
  int c = tid & (CW - 1);
  int bb = tid / CW;
  for (int s = 0; s < LOG; ++s) {
    int h = NB >> s;
    __syncthreads();
#pragma unroll
    for (int u = 0; u < ITER; ++u) {
      int bf = bb + BSTR * u;
      int j = bf & (h - 1);
      int i0 = 2 * bf - j;
      float2 a = A[i0 * CW + c];
      float2 b = A[(i0 + h) * CW + c];
      float ang = (float)SIGN * PI_F * (float)j / (float)h;
      float wi, wr;
      sincosf(ang, &wi, &wr);
      A[i0 * CW + c] = make_float2(a.x + b.x, a.y + b.y);
      float tx = a.x - b.x, ty = a.y - b.y;
      A[(i0 + h) * CW + c] = make_float2(wr * tx - wi * ty, wr * ty + wi * tx);
    }
  }
  __syncthreads();
}

template <int N, int CW, int T, int SIGN>
__device__ inline void dit_mc(float2* A, int tid) {
  const int NB = N / 2;
  const int LOG = (N == 1024) ? 10 : 8;
  const int ITER = (NB * CW) / T;
  const int BSTR = T / CW;
  int c = tid & (CW - 1);
  int bb = tid / CW;
  for (int s = 0; s < LOG; ++s) {
    int m = 1 << s;
    __syncthreads();
#pragma unroll
    for (int u = 0; u < ITER; ++u) {
      int bf = bb + BSTR * u;
      int k = bf & (m - 1);
      int i0 = 2 * bf - k;
      float2 a = A[i0 * CW + c];
      float2 b = A[(i0 + m) * CW + c];
      float ang = (float)SIGN * PI_F * (float)k / (float)m;
      float wi, wr;
      sincosf(ang, &wi, &wr);
      float bx = wr * b.x - wi * b.y, by = wr * b.y + wi * b.x;
      A[i0 * CW + c] = make_float2(a.x + bx, a.y + by);
      A[(i0 + m) * CW + c] = make_float2(a.x - bx, a.y - by);
    }
  }
  __syncthreads();
}

// ---------------- per-batch: YT[l,q,p] = sqrt(Y[b,l,p,q]) as fp16 ----------------
__global__ __launch_bounds__(256) void k_sqrty_bt(
    const float* __restrict__ Y, _Float16* __restrict__ YT, int b) {
  __shared__ float T[32][33];
  int blk = blockIdx.x;          // l*64 + tp*8 + tq
  int tq = blk & 7;
  int tp = (blk >> 3) & 7;
  int l = blk >> 6;              // 0..63
  int tx = threadIdx.x & 31;
  int ty = threadIdx.x >> 5;     // 0..7
  const float* Yb = Y + ((long)b * 64 + l) * 65536;
  _Float16* Tb = YT + (long)l * 65536;
#pragma unroll
  for (int k = 0; k < 4; ++k) {
    int p = tp * 32 + ty + k * 8;
    T[ty + k * 8][tx] = Yb[p * 256 + tq * 32 + tx];
  }
  __syncthreads();
#pragma unroll
  for (int k = 0; k < 4; ++k) {
    int q = tq * 32 + ty + k * 8;
    Tb[(long)q * 256 + tp * 32 + tx] = (_Float16)sqrtf(T[tx][ty + k * 8]);
  }
}

// ---------------- 1024-point row passes (coalesced already) ----------------

__global__ __launch_bounds__(256) void k_fft_rows_big(
    const float* __restrict__ re, const float* __restrict__ im,
    float2* __restrict__ zf) {
  __shared__ float2 A[1024], Bb[1024];
  long base = (long)blockIdx.x * 1024;
  int tid = threadIdx.x;
#pragma unroll
  for (int k = 0; k < 4; ++k) {
    int q = tid + k * 256;
    A[q] = make_float2(re[base + q], im[base + q]);
  }
  float2* res = fft_lds<1024, 256, -1>(A, Bb, tid);
#pragma unroll
  for (int k = 0; k < 4; ++k) {
    int q = tid + k * 256;
    zf[base + ((q + 512) & 1023)] = res[q];
  }
}

__global__ __launch_bounds__(256) void k_ifft_rows_big(float2* __restrict__ U) {
  __shared__ float2 A[1024], Bb[1024];
  long base = (long)blockIdx.x * 1024;
  int tid = threadIdx.x;
#pragma unroll
  for (int k = 0; k < 4; ++k) {
    int q = tid + k * 256;
    A[q] = U[base + ((q + 512) & 1023)];
  }
  float2* res = fft_lds<1024, 256, 1>(A, Bb, tid);
  const float sc = 1.0f / 1024.0f;
#pragma unroll
  for (int k = 0; k < 4; ++k) {
    int q = tid + k * 256;
    U[base + q] = cscale(res[q], sc);
  }
}

// ---------------- 1024-point column passes: multi-column, in-place, coalesced ----------------

// forward col FFT of zf, row fftshift fold on output (natural in -> DIF -> bitrev out)
__global__ __launch_bounds__(256) void k_fft_cols_mc(float2* __restrict__ zf) {
  __shared__ float2 A[8192];  // 1024 x 8 = 64 KB
  int b = blockIdx.x >> 7;
  int c0 = (blockIdx.x & 127) * 8;
  long base = (long)b * 1048576 + c0;
  int tid = threadIdx.x;
#pragma unroll
  for (int u = 0; u < 32; ++u) {
    int v = tid + 256 * u;
    int r = v >> 3, c = v & 7;
    A[v] = zf[base + (long)r * 1024 + c];
  }
  dif_mc<1024, 8, 256, -1>(A, tid);
#pragma unroll
  for (int u = 0; u < 32; ++u) {
    int v = tid + 256 * u;
    int r = v >> 3, c = v & 7;
    int i = (int)(__brev((unsigned)r) >> 22);  // output index held in slot r
    zf[base + (long)((i + 512) & 1023) * 1024 + c] = A[v];
  }
}

// inverse col FFT of U, row ifftshift fold on input (bitrev load -> DIT -> natural out)
__global__ __launch_bounds__(256) void k_ifft_cols_mc(float2* __restrict__ U) {
  __shared__ float2 A[8192];
  int b = blockIdx.x >> 7;
  int c0 = (blockIdx.x & 127) * 8;
  long base = (long)b * 1048576 + c0;
  int tid = threadIdx.x;
#pragma unroll
  for (int u = 0; u < 32; ++u) {
    int v = tid + 256 * u;
    int r = v >> 3, c = v & 7;
    int i = (int)(__brev((unsigned)r) >> 22);  // slot r must hold X[bitrev(r)]
    A[v] = U[base + (long)((i + 512) & 1023) * 1024 + c];
  }
  dit_mc<1024, 8, 256, 1>(A, tid);
  const float sc = 1.0f / 1024.0f;
#pragma unroll
  for (int u = 0; u < 32; ++u) {
    int v = tid + 256 * u;
    int r = v >> 3, c = v & 7;
    U[base + (long)r * 1024 + c] = cscale(A[v], sc);
  }
}

// ---------------- 256-point patch passes (per batch b, chunk l0..l0+nc) ----------------

// pass 1: gather (ifftshift fold) * CTF, inverse ROW FFT, scale 1/256 -> P rows
__global__ __launch_bounds__(128) void k_patch_gather_irows(
    const float2* __restrict__ zf, const int* __restrict__ masks,
    const float* __restrict__ ctf, float2* __restrict__ P, int b, int l0) {
  __shared__ float2 A[256], Bb[256];
  int idx = blockIdx.x;  // li*256 + p
  int p = idx & 255;
  int li = idx >> 8;
  int l = l0 + li;
  int tid = threadIdx.x;
  int br = masks[2 * l] - 1, bc = masks[2 * l + 1] - 1;
  int sp = (p + 128) & 255;
  long zbase = (long)b * (1024 * 1024) + (long)(br + sp) * 1024 + bc;
  const float* crow = ctf + sp * 256;
#pragma unroll
  for (int k = 0; k < 2; ++k) {
    int q = tid + k * 128;
    int sq = (q + 128) & 255;
    float cv = crow[sq];
    float2 v = zf[zbase + sq];
    A[q] = make_float2(v.x * cv, v.y * cv);
  }
  float2* res = fft_lds<256, 128, 1>(A, Bb, tid);
  const float sc = 1.0f / 256.0f;
  long pbase = (long)idx * 256;
#pragma unroll
  for (int k = 0; k < 2; ++k) {
    int q = tid + k * 128;
    P[pbase + q] = cscale(res[q], sc);
  }
}

// pass 2 (fused): col DIT-ifft (1/256) -> Bz; Cz = Bz - sqrtY*Bz/|Bz|; col DIF-fft;
// write back with ROW fftshift fold. 8 columns per block, all I/O coalesced.
__global__ __launch_bounds__(256) void k_patch_cz_mc(
    float2* __restrict__ P, const float* __restrict__ Y,
    const _Float16* __restrict__ YT, int use_yt, int b, int l0) {
  __shared__ float2 A[2048];  // 256 x 8 = 16 KB
  int li = blockIdx.x >> 5;
  int c0 = (blockIdx.x & 31) * 8;
  int l = l0 + li;
  int tid = threadIdx.x;
  long pbase = (long)li * 65536 + c0;
#pragma unroll
  for (int u = 0; u < 8; ++u) {
    int v = tid + 256 * u;
    int r = v >> 3, c = v & 7;
    int i = (int)(__brev((unsigned)r) >> 24);
    A[v] = P[pbase + (long)i * 256 + c];
  }
  dit_mc<256, 8, 256, 1>(A, tid);
  const float sc = 1.0f / 256.0f;
#pragma unroll
  for (int u = 0; u < 8; ++u) {
    int v = tid + 256 * u;
    int i = v >> 3, c = v & 7;   // natural order after DIT
    float2 bz = cscale(A[v], sc);
    float mag = sqrtf(bz.x * bz.x + bz.y * bz.y);
    float s = use_yt ? (float)YT[((long)l * 256 + c0 + c) * 256 + i]
                     : sqrtf(Y[(((long)(b * 64 + l) * 256 + i) * 256) + c0 + c]);
    float2 ph = (mag > 0.0f) ? make_float2(bz.x / mag, bz.y / mag)
                             : make_float2(1.0f, 0.0f);
    A[v] = make_float2(bz.x - s * ph.x, bz.y - s * ph.y);
  }
  dif_mc<256, 8, 256, -1>(A, tid);  // stage-0 barrier covers the writes above
#pragma unroll
  for (int u = 0; u < 8; ++u) {
    int v = tid + 256 * u;
    int r = v >> 3, c = v & 7;
    int i = (int)(__brev((unsigned)r) >> 24);
    P[pbase + (long)((i + 128) & 255) * 256 + c] = A[v];
  }
}

// pass 3: forward ROW FFT; col fftshift fold; * ctf * (1/L); coalesced row scatter
__global__ __launch_bounds__(128) void k_patch_rows_scatter(
    const float2* __restrict__ P, const int* __restrict__ masks,
    const float* __restrict__ ctf, float* __restrict__ U, int b, int l0) {
  __shared__ float2 A[256], Bb[256];
  int idx = blockIdx.x;  // li*256 + p   (p = shifted freq row)
  int p = idx & 255;
  int li = idx >> 8;
  int l = l0 + li;
  int tid = threadIdx.x;
  int br = masks[2 * l] - 1, bc = masks[2 * l + 1] - 1;
  long pbase = (long)idx * 256;
#pragma unroll
  for (int k = 0; k < 2; ++k) {
    int q = tid + k * 128;
    A[q] = P[pbase + q];
  }
  float2* res = fft_lds<256, 128, -1>(A, Bb, tid);
  const float sc = 1.0f / 64.0f;
  long rowbase = ((long)b * (1024 * 1024) + (long)(br + p) * 1024 + bc) * 2;
  const float* crow = ctf + p * 256;
#pragma unroll
  for (int k = 0; k < 2; ++k) {
    int q = tid + k * 128;
    int qp = (q + 128) & 255;
    float cv = crow[qp] * sc;
    float2 v = res[q];
    atomicAdd(&U[rowbase + 2 * qp], v.x * cv);
    atomicAdd(&U[rowbase + 2 * qp + 1], v.y * cv);
  }
}

// ---------------- final combine ----------------
__global__ __launch_bounds__(256) void k_combine(
    const float* __restrict__ Ia, const float* __restrict__ Icr,
    const float* __restrict__ Ici, const float2* __restrict__ W,
    const float* __restrict__ lamb, const float* __restrict__ eta1,
    float* __restrict__ out, long out_elems) {
  long i = (long)blockIdx.x * blockDim.x + threadIdx.x;
  const long NTOT = 4L * 1024 * 1024;
  float e1 = eta1[0], lm = lamb[0];
  float c1 = 100.0f * e1 * lm;
  float c2 = 10.0f * e1;
  float cr = Icr[i], ci = Ici[i], a = Ia[i];
  float mag = sqrtf(cr * cr + ci * ci);
  float t = a / (mag + EPSF);
  float2 w = W[i];
  float rx = cr * (1.0f - c1) + c1 * cr * t - c2 * w.x;
  float ry = ci * (1.0f - c1) + c1 * ci * t - c2 * w.y;
  if (i < out_elems) out[i] = sqrtf(rx * rx + ry * ry);
  if (NTOT + i < out_elems) out[NTOT + i] = rx;
  if (2 * NTOT + i < out_elems) out[2 * NTOT + i] = ry;
}

extern "C" void kernel_launch(void* const* d_in, const int* in_sizes, int n_in,
                              void* d_out, int out_size, void* d_ws, size_t ws_size,
                              hipStream_t stream) {
  (void)in_sizes; (void)n_in;
  const float* Ia   = (const float*)d_in[0];
  const float* Icr  = (const float*)d_in[1];
  const float* Ici  = (const float*)d_in[2];
  const float* Y    = (const float*)d_in[3];
  const int*   Masks = (const int*)d_in[4];
  const float* CTF  = (const float*)d_in[5];
  const float* lamb = (const float*)d_in[6];
  const float* eta1 = (const float*)d_in[7];
  float* out = (float*)d_out;

  const size_t MB32 = 32ull * 1024 * 1024;
  const size_t YTB  = 8ull * 1024 * 1024;
  const size_t PATCH_BYTES = 256 * 256 * sizeof(float2);  // 512 KiB

  char* wsb = (char*)d_ws;
  float2* U = (float2*)wsb;
  size_t used = MB32;
  if (used > ws_size) used = ws_size;

  float2* zf;
  bool zf_in_ws = (ws_size >= MB32 + MB32 + PATCH_BYTES);
  bool zf_in_out = (!zf_in_ws) && ((size_t)out_size * sizeof(float) >= MB32);
  if (zf_in_ws) { zf = (float2*)(wsb + used); used += MB32; }
  else if (zf_in_out) { zf = (float2*)d_out; }
  else { zf = U; }

  _Float16* YT = nullptr;
  int use_yt = 0;
  if (ws_size >= used + YTB + PATCH_BYTES) {
    YT = (_Float16*)(wsb + used);
    used += YTB;
    use_yt = 1;
  }

  size_t rem = (ws_size > used) ? (ws_size - used) : 0;
  long ncl = (long)(rem / PATCH_BYTES);
  int NC = (int)(ncl < 1 ? 1 : (ncl > 64 ? 64 : ncl));
  float2* P = (float2*)(wsb + ((rem >= PATCH_BYTES) ? used : 0));

  size_t zbytes = MB32 <= ws_size ? MB32 : ws_size;
  hipMemsetAsync(U, 0, zbytes, stream);

  k_fft_rows_big<<<4096, 256, 0, stream>>>(Icr, Ici, zf);
  k_fft_cols_mc<<<512, 256, 0, stream>>>(zf);

  for (int b = 0; b < 4; ++b) {
    if (use_yt) k_sqrty_bt<<<4096, 256, 0, stream>>>(Y, YT, b);
    for (int l0 = 0; l0 < 64; l0 += NC) {
      int nc = (64 - l0) < NC ? (64 - l0) : NC;
      k_patch_gather_irows<<<nc * 256, 128, 0, stream>>>(zf, Masks, CTF, P, b, l0);
      k_patch_cz_mc<<<nc * 32, 256, 0, stream>>>(P, Y, YT, use_yt, b, l0);
      k_patch_rows_scatter<<<nc * 256, 128, 0, stream>>>(P, Masks, CTF, (float*)U, b, l0);
    }
  }

  k_ifft_cols_mc<<<512, 256, 0, stream>>>(U);
  k_ifft_rows_big<<<4096, 256, 0, stream>>>(U);

  k_combine<<<16384, 256, 0, stream>>>(Ia, Icr, Ici, U, lamb, eta1, out, (long)out_size);
}

// Round 8
// 741.243 us; speedup vs baseline: 4.3001x; 1.3910x over previous
//
#include <hip/hip_runtime.h>
#include <math.h>

#define PI_F 3.14159265358979323846f
#define EPSF 1e-6f

__device__ inline float2 cscale(float2 a, float s) { return make_float2(a.x * s, a.y * s); }

// fast hardware twiddle: native v_sin/v_cos (~1e-5 twiddle error, fine vs 0.087 threshold)
__device__ inline void twiddle(float ang, float* s, float* c) {
  __sincosf(ang, s, c);
}

// ---------------- Stockham radix-2 FFT in LDS (single column; used by row passes) ----------------
template <int N, int T, int SIGN>
__device__ inline float2* fft_lds(float2* bufA, float2* bufB, int tid) {
  const int NB = N / 2;
  const int BPT = NB / T;
  const int STAGES = (N == 1024) ? 10 : 8;
  float2* src = bufA;
  float2* dst = bufB;
  for (int s = 0; s < STAGES; ++s) {
    const int m = 1 << s;
    const int l = NB >> s;
    __syncthreads();
#pragma unroll
    for (int u = 0; u < BPT; ++u) {
      int bf = tid + u * T;
      int k = bf & (m - 1);
      int j = bf >> s;
      float2 a = src[bf];
      float2 c = src[bf + NB];
      float ang = (float)SIGN * PI_F * (float)j / (float)l;
      float wi, wr;
      twiddle(ang, &wi, &wr);
      float2 d0 = make_float2(a.x + c.x, a.y + c.y);
      float tx = a.x - c.x, ty = a.y - c.y;
      float2 d1 = make_float2(wr * tx - wi * ty, wr * ty + wi * tx);
      int o = 2 * bf - k;
      dst[o] = d0;
      dst[o + m] = d1;
    }
    float2* tmp = src; src = dst; dst = tmp;
  }
  __syncthreads();
  return src;
}

// ---------------- in-place multi-column FFTs (column passes) ----------------
template <int N, int CW, int T, int SIGN>
__device__ inline void dif_mc(float2* A, int tid) {
  const int NB = N / 2;
  const int LOG = (N == 1024) ? 10 : 8;
  const int ITER = (NB * CW) / T;
  const int BSTR = T / CW;
  int c = tid & (CW - 1);
  int bb = tid / CW;
  for (int s = 0; s < LOG; ++s) {
    int h = NB >> s;
    __syncthreads();
#pragma unroll
    for (int u = 0; u < ITER; ++u) {
      int bf = bb + BSTR * u;
      int j = bf & (h - 1);
      int i0 = 2 * bf - j;
      float2 a = A[i0 * CW + c];
      float2 b = A[(i0 + h) * CW + c];
      float ang = (float)SIGN * PI_F * (float)j / (float)h;
      float wi, wr;
      twiddle(ang, &wi, &wr);
      A[i0 * CW + c] = make_float2(a.x + b.x, a.y + b.y);
      float tx = a.x - b.x, ty = a.y - b.y;
      A[(i0 + h) * CW + c] = make_float2(wr * tx - wi * ty, wr * ty + wi * tx);
    }
  }
  __syncthreads();
}

template <int N, int CW, int T, int SIGN>
__device__ inline void dit_mc(float2* A, int tid) {
  const int NB = N / 2;
  const int LOG = (N == 1024) ? 10 : 8;
  const int ITER = (NB * CW) / T;
  const int BSTR = T / CW;
  int c = tid & (CW - 1);
  int bb = tid / CW;
  for (int s = 0; s < LOG; ++s) {
    int m = 1 << s;
    __syncthreads();
#pragma unroll
    for (int u = 0; u < ITER; ++u) {
      int bf = bb + BSTR * u;
      int k = bf & (m - 1);
      int i0 = 2 * bf - k;
      float2 a = A[i0 * CW + c];
      float2 b = A[(i0 + m) * CW + c];
      float ang = (float)SIGN * PI_F * (float)k / (float)m;
      float wi, wr;
      twiddle(ang, &wi, &wr);
      float bx = wr * b.x - wi * b.y, by = wr * b.y + wi * b.x;
      A[i0 * CW + c] = make_float2(a.x + bx, a.y + by);
      A[(i0 + m) * CW + c] = make_float2(a.x - bx, a.y - by);
    }
  }
  __syncthreads();
}

// ---------------- per-batch: YT[l,q,p] = sqrt(Y[b,l,p,q]) as fp16 ----------------
__global__ __launch_bounds__(256) void k_sqrty_bt(
    const float* __restrict__ Y, _Float16* __restrict__ YT, int b) {
  __shared__ float T[32][33];
  int blk = blockIdx.x;          // l*64 + tp*8 + tq
  int tq = blk & 7;
  int tp = (blk >> 3) & 7;
  int l = blk >> 6;              // 0..63
  int tx = threadIdx.x & 31;
  int ty = threadIdx.x >> 5;     // 0..7
  const float* Yb = Y + ((long)b * 64 + l) * 65536;
  _Float16* Tb = YT + (long)l * 65536;
#pragma unroll
  for (int k = 0; k < 4; ++k) {
    int p = tp * 32 + ty + k * 8;
    T[ty + k * 8][tx] = Yb[p * 256 + tq * 32 + tx];
  }
  __syncthreads();
#pragma unroll
  for (int k = 0; k < 4; ++k) {
    int q = tq * 32 + ty + k * 8;
    Tb[(long)q * 256 + tp * 32 + tx] = (_Float16)sqrtf(T[tx][ty + k * 8]);
  }
}

// ---------------- 1024-point row passes ----------------

__global__ __launch_bounds__(256) void k_fft_rows_big(
    const float* __restrict__ re, const float* __restrict__ im,
    float2* __restrict__ zf) {
  __shared__ float2 A[1024], Bb[1024];
  long base = (long)blockIdx.x * 1024;
  int tid = threadIdx.x;
#pragma unroll
  for (int k = 0; k < 4; ++k) {
    int q = tid + k * 256;
    A[q] = make_float2(re[base + q], im[base + q]);
  }
  float2* res = fft_lds<1024, 256, -1>(A, Bb, tid);
#pragma unroll
  for (int k = 0; k < 4; ++k) {
    int q = tid + k * 256;
    zf[base + ((q + 512) & 1023)] = res[q];
  }
}

__global__ __launch_bounds__(256) void k_ifft_rows_big(float2* __restrict__ U) {
  __shared__ float2 A[1024], Bb[1024];
  long base = (long)blockIdx.x * 1024;
  int tid = threadIdx.x;
#pragma unroll
  for (int k = 0; k < 4; ++k) {
    int q = tid + k * 256;
    A[q] = U[base + ((q + 512) & 1023)];
  }
  float2* res = fft_lds<1024, 256, 1>(A, Bb, tid);
  const float sc = 1.0f / 1024.0f;
#pragma unroll
  for (int k = 0; k < 4; ++k) {
    int q = tid + k * 256;
    U[base + q] = cscale(res[q], sc);
  }
}

// ---------------- 1024-point column passes: multi-column, in-place, coalesced ----------------

__global__ __launch_bounds__(256) void k_fft_cols_mc(float2* __restrict__ zf) {
  __shared__ float2 A[8192];  // 1024 x 8 = 64 KB
  int b = blockIdx.x >> 7;
  int c0 = (blockIdx.x & 127) * 8;
  long base = (long)b * 1048576 + c0;
  int tid = threadIdx.x;
#pragma unroll
  for (int u = 0; u < 32; ++u) {
    int v = tid + 256 * u;
    int r = v >> 3, c = v & 7;
    A[v] = zf[base + (long)r * 1024 + c];
  }
  dif_mc<1024, 8, 256, -1>(A, tid);
#pragma unroll
  for (int u = 0; u < 32; ++u) {
    int v = tid + 256 * u;
    int r = v >> 3, c = v & 7;
    int i = (int)(__brev((unsigned)r) >> 22);
    zf[base + (long)((i + 512) & 1023) * 1024 + c] = A[v];
  }
}

__global__ __launch_bounds__(256) void k_ifft_cols_mc(float2* __restrict__ U) {
  __shared__ float2 A[8192];
  int b = blockIdx.x >> 7;
  int c0 = (blockIdx.x & 127) * 8;
  long base = (long)b * 1048576 + c0;
  int tid = threadIdx.x;
#pragma unroll
  for (int u = 0; u < 32; ++u) {
    int v = tid + 256 * u;
    int r = v >> 3, c = v & 7;
    int i = (int)(__brev((unsigned)r) >> 22);
    A[v] = U[base + (long)((i + 512) & 1023) * 1024 + c];
  }
  dit_mc<1024, 8, 256, 1>(A, tid);
  const float sc = 1.0f / 1024.0f;
#pragma unroll
  for (int u = 0; u < 32; ++u) {
    int v = tid + 256 * u;
    int r = v >> 3, c = v & 7;
    U[base + (long)r * 1024 + c] = cscale(A[v], sc);
  }
}

// ---------------- 256-point patch passes (per batch b, chunk l0..l0+nc) ----------------

__global__ __launch_bounds__(128) void k_patch_gather_irows(
    const float2* __restrict__ zf, const int* __restrict__ masks,
    const float* __restrict__ ctf, float2* __restrict__ P, int b, int l0) {
  __shared__ float2 A[256], Bb[256];
  int idx = blockIdx.x;  // li*256 + p
  int p = idx & 255;
  int li = idx >> 8;
  int l = l0 + li;
  int tid = threadIdx.x;
  int br = masks[2 * l] - 1, bc = masks[2 * l + 1] - 1;
  int sp = (p + 128) & 255;
  long zbase = (long)b * (1024 * 1024) + (long)(br + sp) * 1024 + bc;
  const float* crow = ctf + sp * 256;
#pragma unroll
  for (int k = 0; k < 2; ++k) {
    int q = tid + k * 128;
    int sq = (q + 128) & 255;
    float cv = crow[sq];
    float2 v = zf[zbase + sq];
    A[q] = make_float2(v.x * cv, v.y * cv);
  }
  float2* res = fft_lds<256, 128, 1>(A, Bb, tid);
  const float sc = 1.0f / 256.0f;
  long pbase = (long)idx * 256;
#pragma unroll
  for (int k = 0; k < 2; ++k) {
    int q = tid + k * 128;
    P[pbase + q] = cscale(res[q], sc);
  }
}

__global__ __launch_bounds__(256) void k_patch_cz_mc(
    float2* __restrict__ P, const float* __restrict__ Y,
    const _Float16* __restrict__ YT, int use_yt, int b, int l0) {
  __shared__ float2 A[2048];  // 256 x 8 = 16 KB
  int li = blockIdx.x >> 5;
  int c0 = (blockIdx.x & 31) * 8;
  int l = l0 + li;
  int tid = threadIdx.x;
  long pbase = (long)li * 65536 + c0;
#pragma unroll
  for (int u = 0; u < 8; ++u) {
    int v = tid + 256 * u;
    int r = v >> 3, c = v & 7;
    int i = (int)(__brev((unsigned)r) >> 24);
    A[v] = P[pbase + (long)i * 256 + c];
  }
  dit_mc<256, 8, 256, 1>(A, tid);
  const float sc = 1.0f / 256.0f;
#pragma unroll
  for (int u = 0; u < 8; ++u) {
    int v = tid + 256 * u;
    int i = v >> 3, c = v & 7;
    float2 bz = cscale(A[v], sc);
    float mag = sqrtf(bz.x * bz.x + bz.y * bz.y);
    float s = use_yt ? (float)YT[((long)l * 256 + c0 + c) * 256 + i]
                     : sqrtf(Y[(((long)(b * 64 + l) * 256 + i) * 256) + c0 + c]);
    float2 ph = (mag > 0.0f) ? make_float2(bz.x / mag, bz.y / mag)
                             : make_float2(1.0f, 0.0f);
    A[v] = make_float2(bz.x - s * ph.x, bz.y - s * ph.y);
  }
  dif_mc<256, 8, 256, -1>(A, tid);
#pragma unroll
  for (int u = 0; u < 8; ++u) {
    int v = tid + 256 * u;
    int r = v >> 3, c = v & 7;
    int i = (int)(__brev((unsigned)r) >> 24);
    P[pbase + (long)((i + 128) & 255) * 256 + c] = A[v];
  }
}

__global__ __launch_bounds__(128) void k_patch_rows_scatter(
    const float2* __restrict__ P, const int* __restrict__ masks,
    const float* __restrict__ ctf, float* __restrict__ U, int b, int l0) {
  __shared__ float2 A[256], Bb[256];
  int idx = blockIdx.x;  // li*256 + p
  int p = idx & 255;
  int li = idx >> 8;
  int l = l0 + li;
  int tid = threadIdx.x;
  int br = masks[2 * l] - 1, bc = masks[2 * l + 1] - 1;
  long pbase = (long)idx * 256;
#pragma unroll
  for (int k = 0; k < 2; ++k) {
    int q = tid + k * 128;
    A[q] = P[pbase + q];
  }
  float2* res = fft_lds<256, 128, -1>(A, Bb, tid);
  const float sc = 1.0f / 64.0f;
  long rowbase = ((long)b * (1024 * 1024) + (long)(br + p) * 1024 + bc) * 2;
  const float* crow = ctf + p * 256;
#pragma unroll
  for (int k = 0; k < 2; ++k) {
    int q = tid + k * 128;
    int qp = (q + 128) & 255;
    float cv = crow[qp] * sc;
    float2 v = res[q];
    atomicAdd(&U[rowbase + 2 * qp], v.x * cv);
    atomicAdd(&U[rowbase + 2 * qp + 1], v.y * cv);
  }
}

// ---------------- final combine ----------------
__global__ __launch_bounds__(256) void k_combine(
    const float* __restrict__ Ia, const float* __restrict__ Icr,
    const float* __restrict__ Ici, const float2* __restrict__ W,
    const float* __restrict__ lamb, const float* __restrict__ eta1,
    float* __restrict__ out, long out_elems) {
  long i = (long)blockIdx.x * blockDim.x + threadIdx.x;
  const long NTOT = 4L * 1024 * 1024;
  float e1 = eta1[0], lm = lamb[0];
  float c1 = 100.0f * e1 * lm;
  float c2 = 10.0f * e1;
  float cr = Icr[i], ci = Ici[i], a = Ia[i];
  float mag = sqrtf(cr * cr + ci * ci);
  float t = a / (mag + EPSF);
  float2 w = W[i];
  float rx = cr * (1.0f - c1) + c1 * cr * t - c2 * w.x;
  float ry = ci * (1.0f - c1) + c1 * ci * t - c2 * w.y;
  if (i < out_elems) out[i] = sqrtf(rx * rx + ry * ry);
  if (NTOT + i < out_elems) out[NTOT + i] = rx;
  if (2 * NTOT + i < out_elems) out[2 * NTOT + i] = ry;
}

extern "C" void kernel_launch(void* const* d_in, const int* in_sizes, int n_in,
                              void* d_out, int out_size, void* d_ws, size_t ws_size,
                              hipStream_t stream) {
  (void)in_sizes; (void)n_in;
  const float* Ia   = (const float*)d_in[0];
  const float* Icr  = (const float*)d_in[1];
  const float* Ici  = (const float*)d_in[2];
  const float* Y    = (const float*)d_in[3];
  const int*   Masks = (const int*)d_in[4];
  const float* CTF  = (const float*)d_in[5];
  const float* lamb = (const float*)d_in[6];
  const float* eta1 = (const float*)d_in[7];
  float* out = (float*)d_out;

  const size_t MB32 = 32ull * 1024 * 1024;
  const size_t YTB  = 8ull * 1024 * 1024;
  const size_t PATCH_BYTES = 256 * 256 * sizeof(float2);  // 512 KiB

  char* wsb = (char*)d_ws;
  float2* U = (float2*)wsb;
  size_t used = MB32;
  if (used > ws_size) used = ws_size;

  float2* zf;
  bool zf_in_ws = (ws_size >= MB32 + MB32 + PATCH_BYTES);
  bool zf_in_out = (!zf_in_ws) && ((size_t)out_size * sizeof(float) >= MB32);
  if (zf_in_ws) { zf = (float2*)(wsb + used); used += MB32; }
  else if (zf_in_out) { zf = (float2*)d_out; }
  else { zf = U; }

  _Float16* YT = nullptr;
  int use_yt = 0;
  if (ws_size >= used + YTB + PATCH_BYTES) {
    YT = (_Float16*)(wsb + used);
    used += YTB;
    use_yt = 1;
  }

  size_t rem = (ws_size > used) ? (ws_size - used) : 0;
  long ncl = (long)(rem / PATCH_BYTES);
  int NC = (int)(ncl < 1 ? 1 : (ncl > 64 ? 64 : ncl));
  float2* P = (float2*)(wsb + ((rem >= PATCH_BYTES) ? used : 0));

  size_t zbytes = MB32 <= ws_size ? MB32 : ws_size;
  hipMemsetAsync(U, 0, zbytes, stream);

  k_fft_rows_big<<<4096, 256, 0, stream>>>(Icr, Ici, zf);
  k_fft_cols_mc<<<512, 256, 0, stream>>>(zf);

  for (int b = 0; b < 4; ++b) {
    if (use_yt) k_sqrty_bt<<<4096, 256, 0, stream>>>(Y, YT, b);
    for (int l0 = 0; l0 < 64; l0 += NC) {
      int nc = (64 - l0) < NC ? (64 - l0) : NC;
      k_patch_gather_irows<<<nc * 256, 128, 0, stream>>>(zf, Masks, CTF, P, b, l0);
      k_patch_cz_mc<<<nc * 32, 256, 0, stream>>>(P, Y, YT, use_yt, b, l0);
      k_patch_rows_scatter<<<nc * 256, 128, 0, stream>>>(P, Masks, CTF, (float*)U, b, l0);
    }
  }

  k_ifft_cols_mc<<<512, 256, 0, stream>>>(U);
  k_ifft_rows_big<<<4096, 256, 0, stream>>>(U);

  k_combine<<<16384, 256, 0, stream>>>(Ia, Icr, Ici, U, lamb, eta1, out, (long)out_size);
}